// Round 3
// baseline (2416.639 us; speedup 1.0000x reference)
//
#include <hip/hip_runtime.h>

// GPT forward, MI355X gfx950.
// Shapes: V=371 E=512 H=8 L=8 B=4 T=1024 D=64, N=B*T=4096.
// Float tensors may be float32 OR bf16 (device-side runtime detection on wte);
// idx int32; out = logits [B,T,V] in the same float format as the inputs.
// Per-layer weight slices are offset ON-DEVICE (element offset -> byte offset
// depends on detected dtype, host cannot branch on the device flag).

#define VOCAB 371
#define EMB   512
#define NH    8
#define NL    8
#define TS    1024
#define NTOK  4096
#define NEG_INF (-1e30f)

typedef unsigned short ushort_t;
typedef __attribute__((ext_vector_type(8))) short short8;
typedef __attribute__((ext_vector_type(4))) float f32x4;

__device__ inline float bf2f(ushort_t b) {
    unsigned int u = ((unsigned int)b) << 16;
    float f; __builtin_memcpy(&f, &u, 4); return f;
}
__device__ inline ushort_t f2bf(float f) {
    unsigned int u; __builtin_memcpy(&u, &f, 4);
    u = (u + 0x7fff + ((u >> 16) & 1)) >> 16;   // RNE
    return (ushort_t)u;
}

// ---------------- dtype probe: bf16-pair view of fp32 data has garbage low halves
__global__ __launch_bounds__(64) void detect_k(const ushort_t* __restrict__ w,
        int* __restrict__ flag)
{
    int i = threadIdx.x;                       // probe first 64 element-pairs of wte
    float v = bf2f(w[2 * i]);                  // low half of a float32, or an even bf16
    bool ok = (__builtin_fabsf(v) <= 4.0f);    // wte ~ N(0,0.02): true bf16 => small
    unsigned long long m = __ballot(ok);
    if (i == 0) flag[0] = (__popcll(m) >= 56) ? 1 : 0;   // 1 = bf16, 0 = float32
}

// ---------------- ws-too-small sentinel: absmax ~1000 signature ---------------
__global__ __launch_bounds__(256) void sentinel_k(ushort_t* __restrict__ out, int n)
{
    int i = blockIdx.x * 256 + threadIdx.x;
    if (i < n) out[i] = 0x447A;                // bf16 1000.0
}

// ---------------- embedding: x[n,e] = wte[idx[n],e] + wpe[t,e] (fp32 out) ----
__global__ __launch_bounds__(256) void embed_k(const int* __restrict__ idx,
        const void* __restrict__ wte, const void* __restrict__ wpe,
        float* __restrict__ x, const int* __restrict__ flag)
{
    int n = blockIdx.x, tid = threadIdx.x;
    int t = n & (TS - 1);
    int v = idx[n];
    size_t o = (size_t)n * EMB;
    float a0, a1, b0, b1;
    if (*flag) {
        const ushort_t* te = (const ushort_t*)wte; const ushort_t* pe = (const ushort_t*)wpe;
        a0 = bf2f(te[v * EMB + tid]); a1 = bf2f(te[v * EMB + 256 + tid]);
        b0 = bf2f(pe[t * EMB + tid]); b1 = bf2f(pe[t * EMB + 256 + tid]);
    } else {
        const float* te = (const float*)wte; const float* pe = (const float*)wpe;
        a0 = te[v * EMB + tid]; a1 = te[v * EMB + 256 + tid];
        b0 = pe[t * EMB + tid]; b1 = pe[t * EMB + 256 + tid];
    }
    x[o + tid] = a0 + b0;
    x[o + 256 + tid] = a1 + b1;
}

// ---------------- layernorm: out_bf16 = (x-mean)*rsqrt(var+eps)*w -------------
// w slice chosen on-device: element offset woff (layer*EMB).
__global__ __launch_bounds__(256) void ln_k(const float* __restrict__ x,
        const void* __restrict__ w, long woff, ushort_t* __restrict__ out,
        const int* __restrict__ flag)
{
    __shared__ float red[8];
    int n = blockIdx.x, tid = threadIdx.x;
    const float* xr = x + (size_t)n * EMB;
    float a = xr[tid], b = xr[tid + 256];
    float s = a + b;
#pragma unroll
    for (int off = 32; off > 0; off >>= 1) s += __shfl_down(s, off, 64);
    if ((tid & 63) == 0) red[tid >> 6] = s;
    __syncthreads();
    float mean = (red[0] + red[1] + red[2] + red[3]) * (1.0f / EMB);
    float da = a - mean, db = b - mean;
    float s2 = da * da + db * db;
#pragma unroll
    for (int off = 32; off > 0; off >>= 1) s2 += __shfl_down(s2, off, 64);
    if ((tid & 63) == 0) red[4 + (tid >> 6)] = s2;
    __syncthreads();
    float var = (red[4] + red[5] + red[6] + red[7]) * (1.0f / EMB);
    float rs = rsqrtf(var + 1e-5f);
    float g0, g1;
    if (*flag) {
        const ushort_t* wb = (const ushort_t*)w + woff;
        g0 = bf2f(wb[tid]); g1 = bf2f(wb[tid + 256]);
    } else {
        const float* wf = (const float*)w + woff;
        g0 = wf[tid]; g1 = wf[tid + 256];
    }
    size_t o = (size_t)n * EMB;
    out[o + tid]       = f2bf(da * rs * g0);
    out[o + 256 + tid] = f2bf(db * rs * g1);
}

// ---------------- GEMM: C[M,N] = A[M,K](bf16) * B(weight, flag dtype) ---------
// boff = element offset of this layer's slice in B (applied on-device).
// bt=1: B stored [N,K] (NT, e.g. wte). bt=0: B stored [K,N], staged through an
// in-LDS transpose so the MFMA B-fragment read stays ds_read_b128.
// 64x64 tile, BK=32, 256 thr (4 waves, wave w -> rows w*16..+15).
// Epilogue: optional fp32 residual add, optional exact GELU; out to fp32 buf,
// bf16 buf, or flag-typed buffer outD (logits).
__global__ __launch_bounds__(256) void gemm_k(const ushort_t* __restrict__ A,
        const void* __restrict__ B, long boff, int M, int N, int K, int bt,
        float* __restrict__ outF, ushort_t* __restrict__ outB, void* __restrict__ outD,
        const float* __restrict__ res, int act, const int* __restrict__ flag)
{
    __shared__ ushort_t Al[64 * 40];   // stride 40 bf16 = 80B (16B-aligned, 2-way bank free)
    __shared__ ushort_t Bl[64 * 40];   // [n][k]
    const int isbf = *flag;
    const int tid = threadIdx.x;
    const int wave = tid >> 6, lane = tid & 63;
    const int quad = lane >> 4, l16 = lane & 15;
    const int m0 = blockIdx.y * 64, n0 = blockIdx.x * 64;
    const int sr = tid >> 2, sc = (tid & 3) * 8;       // A stage / bt=1 B stage
    const int kr = tid >> 3, nc = (tid & 7) * 8;       // bt=0 B stage
    f32x4 acc[4] = {};
    const bool bok = (n0 + sr) < N;                    // bt=1 row guard
    const ushort_t* Ag   = A + (size_t)(m0 + sr) * K + sc;
    const ushort_t* Bb   = (const ushort_t*)B + boff;
    const float*    Bf   = (const float*)B + boff;
    const size_t i1 = (size_t)(n0 + sr) * K + sc;      // bt=1 base elem index
    const size_t i0 = (size_t)kr * N + n0 + nc;        // bt=0 base elem index
    for (int k0 = 0; k0 < K; k0 += 32) {
        uint4 av = *(const uint4*)(Ag + k0);
        ushort_t b8[8] = {0, 0, 0, 0, 0, 0, 0, 0};
        size_t bi = bt ? (i1 + k0) : (i0 + (size_t)k0 * N);
        if (!bt || bok) {
            if (isbf) {
                *(uint4*)b8 = *(const uint4*)(Bb + bi);
            } else {
                float4 f0 = *(const float4*)(Bf + bi);
                float4 f1 = *(const float4*)(Bf + bi + 4);
                b8[0] = f2bf(f0.x); b8[1] = f2bf(f0.y); b8[2] = f2bf(f0.z); b8[3] = f2bf(f0.w);
                b8[4] = f2bf(f1.x); b8[5] = f2bf(f1.y); b8[6] = f2bf(f1.z); b8[7] = f2bf(f1.w);
            }
        }
        __syncthreads();
        *(uint4*)&Al[sr * 40 + sc] = av;
        if (bt) {
            *(uint4*)&Bl[sr * 40 + sc] = *(uint4*)b8;
        } else {
#pragma unroll
            for (int i = 0; i < 8; ++i) Bl[(nc + i) * 40 + kr] = b8[i];  // transpose to [n][k]
        }
        __syncthreads();
        short8 af = *(const short8*)&Al[(wave * 16 + l16) * 40 + quad * 8];
#pragma unroll
        for (int nt = 0; nt < 4; ++nt) {
            short8 bf = *(const short8*)&Bl[(nt * 16 + l16) * 40 + quad * 8];
            acc[nt] = __builtin_amdgcn_mfma_f32_16x16x32_bf16(af, bf, acc[nt], 0, 0, 0);
        }
    }
    const int mb = m0 + wave * 16 + quad * 4;   // C-layout: row=(lane>>4)*4+r, col=lane&15
#pragma unroll
    for (int nt = 0; nt < 4; ++nt) {
        int nn = n0 + nt * 16 + l16;
        if (nn >= N) continue;
#pragma unroll
        for (int r = 0; r < 4; ++r) {
            size_t o = (size_t)(mb + r) * N + nn;
            float v = acc[nt][r];
            if (res) v += res[o];
            if (act) v = 0.5f * v * (1.0f + erff(v * 0.70710678118f));
            if (outF)      outF[o] = v;
            else if (outB) outB[o] = f2bf(v);
            else if (isbf) ((ushort_t*)outD)[o] = f2bf(v);
            else           ((float*)outD)[o] = v;
        }
    }
}

// ---------------- flash attention (causal), MFMA ------------------------------
// qkv bf16 [N,1536] rows = [q|k|v]; grid (T/64, B*H); 256 thr, wave w owns 16 q-rows.
__global__ __launch_bounds__(256) void attn_k(const ushort_t* __restrict__ qkv,
        ushort_t* __restrict__ y)
{
    __shared__ ushort_t Kl[32 * 72];      // [key][d]  stride 72
    __shared__ ushort_t Vt[64 * 40];      // [d][key]  stride 40
    __shared__ ushort_t Pl[4][16 * 40];   // per-wave [q][key] stride 40
    const int tid = threadIdx.x, wave = tid >> 6, lane = tid & 63;
    const int quad = lane >> 4, l16 = lane & 15;
    const int qt = blockIdx.x;
    const int b = blockIdx.y >> 3, h = blockIdx.y & 7;
    const int q0b = qt * 64;
    const int q0w = q0b + wave * 16;
    const size_t rstr = 3 * EMB;
    const ushort_t* qbase = qkv + ((size_t)(b * TS) + q0w + l16) * rstr + h * 64;
    short8 qf0 = *(const short8*)(qbase + quad * 8);
    short8 qf1 = *(const short8*)(qbase + 32 + quad * 8);
    f32x4 O[4] = {};
    float m_i[4], l_i[4];
#pragma unroll
    for (int r = 0; r < 4; ++r) { m_i[r] = NEG_INF; l_i[r] = 0.f; }
    const int skey = tid >> 3;         // 0..31
    const int sdc = (tid & 7) * 8;     // 0..56
    const int nkt = (q0b + 64) / 32;
    for (int kt = 0; kt < nkt; ++kt) {
        int k0 = kt * 32;
        const ushort_t* krow = qkv + ((size_t)(b * TS) + k0 + skey) * rstr + EMB + h * 64 + sdc;
        uint4 kv = *(const uint4*)krow;
        uint4 vv = *(const uint4*)(krow + EMB);
        __syncthreads();                       // prior tile's PV reads done
        *(uint4*)&Kl[skey * 72 + sdc] = kv;
        ushort_t vtmp[8]; *(uint4*)vtmp = vv;
#pragma unroll
        for (int i = 0; i < 8; ++i) Vt[(sdc + i) * 40 + skey] = vtmp[i];   // transpose V
        __syncthreads();
        const bool active = (k0 <= q0w + 15);
        if (active) {
            f32x4 S[2] = {};
#pragma unroll
            for (int nt = 0; nt < 2; ++nt) {
                short8 kf0 = *(const short8*)&Kl[(nt * 16 + l16) * 72 + quad * 8];
                short8 kf1 = *(const short8*)&Kl[(nt * 16 + l16) * 72 + 32 + quad * 8];
                S[nt] = __builtin_amdgcn_mfma_f32_16x16x32_bf16(qf0, kf0, S[nt], 0, 0, 0);
                S[nt] = __builtin_amdgcn_mfma_f32_16x16x32_bf16(qf1, kf1, S[nt], 0, 0, 0);
            }
            float p[2][4];
#pragma unroll
            for (int r = 0; r < 4; ++r) {
                int q = q0w + quad * 4 + r;
                float s0 = S[0][r] * 0.125f;
                float s1 = S[1][r] * 0.125f;
                if (k0 + l16 > q)      s0 = NEG_INF;   // causal mask
                if (k0 + 16 + l16 > q) s1 = NEG_INF;
                float mx = fmaxf(s0, s1);
#pragma unroll
                for (int off = 8; off; off >>= 1) mx = fmaxf(mx, __shfl_xor(mx, off, 64));
                float mnew = fmaxf(m_i[r], mx);
                float alpha = __expf(m_i[r] - mnew);
                float p0 = __expf(s0 - mnew);
                float p1 = __expf(s1 - mnew);
                float rsum = p0 + p1;
#pragma unroll
                for (int off = 8; off; off >>= 1) rsum += __shfl_xor(rsum, off, 64);
                l_i[r] = l_i[r] * alpha + rsum;
                m_i[r] = mnew;
#pragma unroll
                for (int dt = 0; dt < 4; ++dt) O[dt][r] *= alpha;
                p[0][r] = p0; p[1][r] = p1;
            }
#pragma unroll
            for (int nt = 0; nt < 2; ++nt)
#pragma unroll
                for (int r = 0; r < 4; ++r)
                    Pl[wave][(quad * 4 + r) * 40 + nt * 16 + l16] = f2bf(p[nt][r]);
        }
        __syncthreads();                       // P visible
        if (active) {
            short8 pf = *(const short8*)&Pl[wave][l16 * 40 + quad * 8];  // A-layout read
#pragma unroll
            for (int dt = 0; dt < 4; ++dt) {
                short8 vf = *(const short8*)&Vt[(dt * 16 + l16) * 40 + quad * 8];
                O[dt] = __builtin_amdgcn_mfma_f32_16x16x32_bf16(pf, vf, O[dt], 0, 0, 0);
            }
        }
    }
#pragma unroll
    for (int dt = 0; dt < 4; ++dt)
#pragma unroll
        for (int r = 0; r < 4; ++r) {
            int q = q0w + quad * 4 + r;
            float v = O[dt][r] / l_i[r];
            y[((size_t)(b * TS) + q) * EMB + h * 64 + dt * 16 + l16] = f2bf(v);
        }
}

// ---------------- host ---------------------------------------------------------
extern "C" void kernel_launch(void* const* d_in, const int* in_sizes, int n_in,
                              void* d_out, int out_size, void* d_ws, size_t ws_size,
                              hipStream_t stream)
{
    const int*  idx    = (const int*)d_in[0];
    const void* wte    = d_in[1];
    const void* wpe    = d_in[2];
    const void* attn_w = d_in[3];   // [L,512,1536]
    const void* proj_w = d_in[4];   // [L,512,512]
    const void* fc_w   = d_in[5];   // [L,512,2048]
    const void* fcp_w  = d_in[6];   // [L,2048,512]
    const void* ln1_w  = d_in[7];
    const void* ln2_w  = d_in[8];
    const void* lnf_w  = d_in[9];

    // ws: flag(256B) + xw fp32[4096,512] + hbf bf16[4096,512] + big bf16[4096,2048]
    size_t need = 256 + (size_t)NTOK * EMB * 4 + (size_t)NTOK * EMB * 2
                + (size_t)NTOK * 2048 * 2;
    if (ws_size < need) {   // distinct failure signature: absmax ~1000
        sentinel_k<<<(out_size + 255) / 256, 256, 0, stream>>>((ushort_t*)d_out, out_size);
        return;
    }
    int* flag = (int*)d_ws;
    char* p = (char*)d_ws + 256;
    float*    xw  = (float*)p;    p += (size_t)NTOK * EMB * 4;
    ushort_t* hbf = (ushort_t*)p; p += (size_t)NTOK * EMB * 2;
    ushort_t* big = (ushort_t*)p; p += (size_t)NTOK * 2048 * 2;

    detect_k<<<1, 64, 0, stream>>>((const ushort_t*)wte, flag);
    embed_k<<<NTOK, 256, 0, stream>>>(idx, wte, wpe, xw, flag);

    for (int l = 0; l < NL; ++l) {
        ln_k<<<NTOK, 256, 0, stream>>>(xw, ln1_w, (long)l * EMB, hbf, flag);
        gemm_k<<<dim3(24, 64), 256, 0, stream>>>(hbf, attn_w, (long)l * 512 * 1536,
                NTOK, 1536, 512, 0, nullptr, big, nullptr, nullptr, 0, flag);
        attn_k<<<dim3(16, 32), 256, 0, stream>>>(big, hbf);   // hbf now = attn y
        gemm_k<<<dim3(8, 64), 256, 0, stream>>>(hbf, proj_w, (long)l * 512 * 512,
                NTOK, 512, 512, 0, xw, nullptr, nullptr, xw, 0, flag);
        ln_k<<<NTOK, 256, 0, stream>>>(xw, ln2_w, (long)l * EMB, hbf, flag);
        gemm_k<<<dim3(32, 64), 256, 0, stream>>>(hbf, fc_w, (long)l * 512 * 2048,
                NTOK, 2048, 512, 0, nullptr, big, nullptr, nullptr, 1 /*gelu*/, flag);
        gemm_k<<<dim3(8, 64), 256, 0, stream>>>(big, fcp_w, (long)l * 2048 * 512,
                NTOK, 512, 2048, 0, xw, nullptr, nullptr, xw, 0, flag);
    }

    ln_k<<<NTOK, 256, 0, stream>>>(xw, lnf_w, 0, hbf, flag);
    // logits = h @ wte^T : wte [V,512] is already [N,K] -> bt=1, flag-typed out
    gemm_k<<<dim3(6, 64), 256, 0, stream>>>(hbf, wte, 0,
            NTOK, VOCAB, 512, 1, nullptr, nullptr, d_out, nullptr, 0, flag);
}

// Round 4
// 1514.979 us; speedup vs baseline: 1.5952x; 1.5952x over previous
//
#include <hip/hip_runtime.h>

// GPT forward, MI355X gfx950.
// Shapes: V=371 E=512 H=8 L=8 B=4 T=1024 D=64, N=B*T=4096.
// Inputs confirmed float32 (r3: flag-driven dual path fixed r2's NaN); output fp32.
// Dtype still runtime-detected for robustness. Fast path: per-layer weight
// transpose+convert to bf16 [N,K] once, then clean NT bf16 MFMA GEMMs.

#define VOCAB 371
#define EMB   512
#define NH    8
#define NL    8
#define TS    1024
#define NTOK  4096
#define NEG_INF (-1e30f)

typedef unsigned short ushort_t;
typedef __attribute__((ext_vector_type(8))) short short8;
typedef __attribute__((ext_vector_type(4))) float f32x4;

__device__ inline float bf2f(ushort_t b) {
    unsigned int u = ((unsigned int)b) << 16;
    float f; __builtin_memcpy(&f, &u, 4); return f;
}
__device__ inline ushort_t f2bf(float f) {
    unsigned int u; __builtin_memcpy(&u, &f, 4);
    u = (u + 0x7fff + ((u >> 16) & 1)) >> 16;   // RNE
    return (ushort_t)u;
}

// ---------------- dtype probe: bf16-pair view of fp32 data has garbage low halves
__global__ __launch_bounds__(64) void detect_k(const ushort_t* __restrict__ w,
        int* __restrict__ flag)
{
    int i = threadIdx.x;
    float v = bf2f(w[2 * i]);
    bool ok = (__builtin_fabsf(v) <= 4.0f);
    unsigned long long m = __ballot(ok);
    if (i == 0) flag[0] = (__popcll(m) >= 56) ? 1 : 0;   // 1 = bf16, 0 = float32
}

// ---------------- ws-too-small sentinel: absmax ~1000 signature ---------------
__global__ __launch_bounds__(256) void sentinel_k(ushort_t* __restrict__ out, int n)
{
    int i = blockIdx.x * 256 + threadIdx.x;
    if (i < n) out[i] = 0x447A;
}

// ---------------- embedding ----------------------------------------------------
__global__ __launch_bounds__(256) void embed_k(const int* __restrict__ idx,
        const void* __restrict__ wte, const void* __restrict__ wpe,
        float* __restrict__ x, const int* __restrict__ flag)
{
    int n = blockIdx.x, tid = threadIdx.x;
    int t = n & (TS - 1);
    int v = idx[n];
    size_t o = (size_t)n * EMB;
    float a0, a1, b0, b1;
    if (*flag) {
        const ushort_t* te = (const ushort_t*)wte; const ushort_t* pe = (const ushort_t*)wpe;
        a0 = bf2f(te[v * EMB + tid]); a1 = bf2f(te[v * EMB + 256 + tid]);
        b0 = bf2f(pe[t * EMB + tid]); b1 = bf2f(pe[t * EMB + 256 + tid]);
    } else {
        const float* te = (const float*)wte; const float* pe = (const float*)wpe;
        a0 = te[v * EMB + tid]; a1 = te[v * EMB + 256 + tid];
        b0 = pe[t * EMB + tid]; b1 = pe[t * EMB + 256 + tid];
    }
    x[o + tid] = a0 + b0;
    x[o + 256 + tid] = a1 + b1;
}

// ---------------- layernorm ----------------------------------------------------
__global__ __launch_bounds__(256) void ln_k(const float* __restrict__ x,
        const void* __restrict__ w, long woff, ushort_t* __restrict__ out,
        const int* __restrict__ flag)
{
    __shared__ float red[8];
    int n = blockIdx.x, tid = threadIdx.x;
    const float* xr = x + (size_t)n * EMB;
    float a = xr[tid], b = xr[tid + 256];
    float s = a + b;
#pragma unroll
    for (int off = 32; off > 0; off >>= 1) s += __shfl_down(s, off, 64);
    if ((tid & 63) == 0) red[tid >> 6] = s;
    __syncthreads();
    float mean = (red[0] + red[1] + red[2] + red[3]) * (1.0f / EMB);
    float da = a - mean, db = b - mean;
    float s2 = da * da + db * db;
#pragma unroll
    for (int off = 32; off > 0; off >>= 1) s2 += __shfl_down(s2, off, 64);
    if ((tid & 63) == 0) red[4 + (tid >> 6)] = s2;
    __syncthreads();
    float var = (red[4] + red[5] + red[6] + red[7]) * (1.0f / EMB);
    float rs = rsqrtf(var + 1e-5f);
    float g0, g1;
    if (*flag) {
        const ushort_t* wb = (const ushort_t*)w + woff;
        g0 = bf2f(wb[tid]); g1 = bf2f(wb[tid + 256]);
    } else {
        const float* wf = (const float*)w + woff;
        g0 = wf[tid]; g1 = wf[tid + 256];
    }
    size_t o = (size_t)n * EMB;
    out[o + tid]       = f2bf(da * rs * g0);
    out[o + 256 + tid] = f2bf(db * rs * g1);
}

// ---------------- per-layer weight transpose+convert: [K,N] dtype -> bf16 [N,K]
// One dispatch handles all 4 weights of layer l; 3072 blocks of 32x32 tiles.
//   seg0 attn [512,1536]  tiles 48x16 = 768   out off 0
//   seg1 proj [512,512]   tiles 16x16 = 256   out off 786432
//   seg2 fc   [512,2048]  tiles 64x16 = 1024  out off 1048576
//   seg3 fcp  [2048,512]  tiles 16x64 = 1024  out off 2097152
__global__ __launch_bounds__(256) void wtrans_k(const void* __restrict__ aw,
        const void* __restrict__ pw, const void* __restrict__ fw,
        const void* __restrict__ fpw, long l, ushort_t* __restrict__ wbuf,
        const int* __restrict__ flag)
{
    __shared__ float tile[32][33];
    const int isbf = *flag;
    int t = blockIdx.x;
    const void* src; ushort_t* dst; int Kw, Nw; long ioff;
    if (t < 768)       { src = aw;  dst = wbuf;           Kw = 512;  Nw = 1536; ioff = l * 512L * 1536; }
    else if (t < 1024) { t -= 768;  src = pw;  dst = wbuf + 786432;  Kw = 512;  Nw = 512;  ioff = l * 512L * 512; }
    else if (t < 2048) { t -= 1024; src = fw;  dst = wbuf + 1048576; Kw = 512;  Nw = 2048; ioff = l * 512L * 2048; }
    else               { t -= 2048; src = fpw; dst = wbuf + 2097152; Kw = 2048; Nw = 512;  ioff = l * 2048L * 512; }
    int tpn = Nw >> 5;
    int n0 = (t % tpn) * 32, k0 = (t / tpn) * 32;
    int tx = threadIdx.x & 31, ty = threadIdx.x >> 5;
#pragma unroll
    for (int i = 0; i < 4; ++i) {
        int r = ty + i * 8;
        size_t ii = ioff + (size_t)(k0 + r) * Nw + n0 + tx;
        tile[r][tx] = isbf ? bf2f(((const ushort_t*)src)[ii]) : ((const float*)src)[ii];
    }
    __syncthreads();
#pragma unroll
    for (int i = 0; i < 4; ++i)
        dst[(size_t)(n0 + ty + i * 8) * Kw + k0 + tx] = f2bf(tile[tx][ty + i * 8]);
}

// ---------------- wte convert: dtype -> bf16 (layout kept [V,512]) -------------
__global__ __launch_bounds__(256) void wconv_k(const void* __restrict__ in,
        ushort_t* __restrict__ out, int n, const int* __restrict__ flag)
{
    int i = blockIdx.x * 256 + threadIdx.x;
    if (i >= n) return;
    out[i] = (*flag) ? ((const ushort_t*)in)[i] : f2bf(((const float*)in)[i]);
}

// ---------------- fast NT GEMM: C[M,N] = A[M,K](bf16) * Bt[N,K](bf16)^T --------
// 64x64 tile, BK=64, 256 thr (4 waves; wave w -> rows w*16..+15).
// LDS stride 72 elems (144 B, 16B-aligned). Per iter/thread: 2 uint4 loads +
// 2 ds_write_b128; per wave: 10 ds_read_b128 + 8 MFMA between 2 barriers.
// Epilogue: optional fp32 residual add, exact GELU; out fp32 / bf16 / flag-typed.
__global__ __launch_bounds__(256) void gemm_nt(const ushort_t* __restrict__ A,
        const ushort_t* __restrict__ Bt, int M, int N, int K,
        float* __restrict__ outF, ushort_t* __restrict__ outB, void* __restrict__ outD,
        const float* __restrict__ res, int act, const int* __restrict__ flag)
{
    __shared__ ushort_t Al[64 * 72];
    __shared__ ushort_t Bl[64 * 72];
    const int isbf = *flag;
    const int tid = threadIdx.x;
    const int wave = tid >> 6, lane = tid & 63;
    const int quad = lane >> 4, l16 = lane & 15;
    const int m0 = blockIdx.y * 64, n0 = blockIdx.x * 64;
    const int sr = tid >> 2, sc = (tid & 3) * 16;
    const bool bok = (n0 + sr) < N;
    const ushort_t* Ag = A + (size_t)(m0 + sr) * K + sc;
    const ushort_t* Bg = Bt + (size_t)(n0 + sr) * K + sc;
    f32x4 acc[4] = {};
    for (int k0 = 0; k0 < K; k0 += 64) {
        uint4 a0 = *(const uint4*)(Ag + k0);
        uint4 a1 = *(const uint4*)(Ag + k0 + 8);
        uint4 b0 = make_uint4(0, 0, 0, 0), b1 = make_uint4(0, 0, 0, 0);
        if (bok) { b0 = *(const uint4*)(Bg + k0); b1 = *(const uint4*)(Bg + k0 + 8); }
        __syncthreads();
        *(uint4*)&Al[sr * 72 + sc] = a0; *(uint4*)&Al[sr * 72 + sc + 8] = a1;
        *(uint4*)&Bl[sr * 72 + sc] = b0; *(uint4*)&Bl[sr * 72 + sc + 8] = b1;
        __syncthreads();
#pragma unroll
        for (int kc = 0; kc < 2; ++kc) {
            short8 af = *(const short8*)&Al[(wave * 16 + l16) * 72 + kc * 32 + quad * 8];
#pragma unroll
            for (int nt = 0; nt < 4; ++nt) {
                short8 bf = *(const short8*)&Bl[(nt * 16 + l16) * 72 + kc * 32 + quad * 8];
                acc[nt] = __builtin_amdgcn_mfma_f32_16x16x32_bf16(af, bf, acc[nt], 0, 0, 0);
            }
        }
    }
    const int mb = m0 + wave * 16 + quad * 4;   // C-layout: row=(lane>>4)*4+r, col=lane&15
#pragma unroll
    for (int nt = 0; nt < 4; ++nt) {
        int nn = n0 + nt * 16 + l16;
        if (nn >= N) continue;
#pragma unroll
        for (int r = 0; r < 4; ++r) {
            size_t o = (size_t)(mb + r) * N + nn;
            float v = acc[nt][r];
            if (res) v += res[o];
            if (act) v = 0.5f * v * (1.0f + erff(v * 0.70710678118f));
            if (outF)      outF[o] = v;
            else if (outB) outB[o] = f2bf(v);
            else if (isbf) ((ushort_t*)outD)[o] = f2bf(v);
            else           ((float*)outD)[o] = v;
        }
    }
}

// ---------------- legacy GEMM (fallback when ws too small for fast path) -------
__global__ __launch_bounds__(256) void gemm_k(const ushort_t* __restrict__ A,
        const void* __restrict__ B, long boff, int M, int N, int K, int bt,
        float* __restrict__ outF, ushort_t* __restrict__ outB, void* __restrict__ outD,
        const float* __restrict__ res, int act, const int* __restrict__ flag)
{
    __shared__ ushort_t Al[64 * 40];
    __shared__ ushort_t Bl[64 * 40];
    const int isbf = *flag;
    const int tid = threadIdx.x;
    const int wave = tid >> 6, lane = tid & 63;
    const int quad = lane >> 4, l16 = lane & 15;
    const int m0 = blockIdx.y * 64, n0 = blockIdx.x * 64;
    const int sr = tid >> 2, sc = (tid & 3) * 8;
    const int kr = tid >> 3, nc = (tid & 7) * 8;
    f32x4 acc[4] = {};
    const bool bok = (n0 + sr) < N;
    const ushort_t* Ag = A + (size_t)(m0 + sr) * K + sc;
    const ushort_t* Bb = (const ushort_t*)B + boff;
    const float*    Bf = (const float*)B + boff;
    const size_t i1 = (size_t)(n0 + sr) * K + sc;
    const size_t i0 = (size_t)kr * N + n0 + nc;
    for (int k0 = 0; k0 < K; k0 += 32) {
        uint4 av = *(const uint4*)(Ag + k0);
        ushort_t b8[8] = {0, 0, 0, 0, 0, 0, 0, 0};
        size_t bi = bt ? (i1 + k0) : (i0 + (size_t)k0 * N);
        if (!bt || bok) {
            if (isbf) *(uint4*)b8 = *(const uint4*)(Bb + bi);
            else {
                float4 f0 = *(const float4*)(Bf + bi);
                float4 f1 = *(const float4*)(Bf + bi + 4);
                b8[0] = f2bf(f0.x); b8[1] = f2bf(f0.y); b8[2] = f2bf(f0.z); b8[3] = f2bf(f0.w);
                b8[4] = f2bf(f1.x); b8[5] = f2bf(f1.y); b8[6] = f2bf(f1.z); b8[7] = f2bf(f1.w);
            }
        }
        __syncthreads();
        *(uint4*)&Al[sr * 40 + sc] = av;
        if (bt) *(uint4*)&Bl[sr * 40 + sc] = *(uint4*)b8;
        else {
#pragma unroll
            for (int i = 0; i < 8; ++i) Bl[(nc + i) * 40 + kr] = b8[i];
        }
        __syncthreads();
        short8 af = *(const short8*)&Al[(wave * 16 + l16) * 40 + quad * 8];
#pragma unroll
        for (int nt = 0; nt < 4; ++nt) {
            short8 bf = *(const short8*)&Bl[(nt * 16 + l16) * 40 + quad * 8];
            acc[nt] = __builtin_amdgcn_mfma_f32_16x16x32_bf16(af, bf, acc[nt], 0, 0, 0);
        }
    }
    const int mb = m0 + wave * 16 + quad * 4;
#pragma unroll
    for (int nt = 0; nt < 4; ++nt) {
        int nn = n0 + nt * 16 + l16;
        if (nn >= N) continue;
#pragma unroll
        for (int r = 0; r < 4; ++r) {
            size_t o = (size_t)(mb + r) * N + nn;
            float v = acc[nt][r];
            if (res) v += res[o];
            if (act) v = 0.5f * v * (1.0f + erff(v * 0.70710678118f));
            if (outF)      outF[o] = v;
            else if (outB) outB[o] = f2bf(v);
            else if (isbf) ((ushort_t*)outD)[o] = f2bf(v);
            else           ((float*)outD)[o] = v;
        }
    }
}

// ---------------- flash attention (causal), MFMA ------------------------------
__global__ __launch_bounds__(256) void attn_k(const ushort_t* __restrict__ qkv,
        ushort_t* __restrict__ y)
{
    __shared__ ushort_t Kl[32 * 72];
    __shared__ ushort_t Vt[64 * 40];
    __shared__ ushort_t Pl[4][16 * 40];
    const int tid = threadIdx.x, wave = tid >> 6, lane = tid & 63;
    const int quad = lane >> 4, l16 = lane & 15;
    const int qt = blockIdx.x;
    const int b = blockIdx.y >> 3, h = blockIdx.y & 7;
    const int q0b = qt * 64;
    const int q0w = q0b + wave * 16;
    const size_t rstr = 3 * EMB;
    const ushort_t* qbase = qkv + ((size_t)(b * TS) + q0w + l16) * rstr + h * 64;
    short8 qf0 = *(const short8*)(qbase + quad * 8);
    short8 qf1 = *(const short8*)(qbase + 32 + quad * 8);
    f32x4 O[4] = {};
    float m_i[4], l_i[4];
#pragma unroll
    for (int r = 0; r < 4; ++r) { m_i[r] = NEG_INF; l_i[r] = 0.f; }
    const int skey = tid >> 3;
    const int sdc = (tid & 7) * 8;
    const int nkt = (q0b + 64) / 32;
    for (int kt = 0; kt < nkt; ++kt) {
        int k0 = kt * 32;
        const ushort_t* krow = qkv + ((size_t)(b * TS) + k0 + skey) * rstr + EMB + h * 64 + sdc;
        uint4 kv = *(const uint4*)krow;
        uint4 vv = *(const uint4*)(krow + EMB);
        __syncthreads();
        *(uint4*)&Kl[skey * 72 + sdc] = kv;
        ushort_t vtmp[8]; *(uint4*)vtmp = vv;
#pragma unroll
        for (int i = 0; i < 8; ++i) Vt[(sdc + i) * 40 + skey] = vtmp[i];
        __syncthreads();
        const bool active = (k0 <= q0w + 15);
        if (active) {
            f32x4 S[2] = {};
#pragma unroll
            for (int nt = 0; nt < 2; ++nt) {
                short8 kf0 = *(const short8*)&Kl[(nt * 16 + l16) * 72 + quad * 8];
                short8 kf1 = *(const short8*)&Kl[(nt * 16 + l16) * 72 + 32 + quad * 8];
                S[nt] = __builtin_amdgcn_mfma_f32_16x16x32_bf16(qf0, kf0, S[nt], 0, 0, 0);
                S[nt] = __builtin_amdgcn_mfma_f32_16x16x32_bf16(qf1, kf1, S[nt], 0, 0, 0);
            }
            float p[2][4];
#pragma unroll
            for (int r = 0; r < 4; ++r) {
                int q = q0w + quad * 4 + r;
                float s0 = S[0][r] * 0.125f;
                float s1 = S[1][r] * 0.125f;
                if (k0 + l16 > q)      s0 = NEG_INF;
                if (k0 + 16 + l16 > q) s1 = NEG_INF;
                float mx = fmaxf(s0, s1);
#pragma unroll
                for (int off = 8; off; off >>= 1) mx = fmaxf(mx, __shfl_xor(mx, off, 64));
                float mnew = fmaxf(m_i[r], mx);
                float alpha = __expf(m_i[r] - mnew);
                float p0 = __expf(s0 - mnew);
                float p1 = __expf(s1 - mnew);
                float rsum = p0 + p1;
#pragma unroll
                for (int off = 8; off; off >>= 1) rsum += __shfl_xor(rsum, off, 64);
                l_i[r] = l_i[r] * alpha + rsum;
                m_i[r] = mnew;
#pragma unroll
                for (int dt = 0; dt < 4; ++dt) O[dt][r] *= alpha;
                p[0][r] = p0; p[1][r] = p1;
            }
#pragma unroll
            for (int nt = 0; nt < 2; ++nt)
#pragma unroll
                for (int r = 0; r < 4; ++r)
                    Pl[wave][(quad * 4 + r) * 40 + nt * 16 + l16] = f2bf(p[nt][r]);
        }
        __syncthreads();
        if (active) {
            short8 pf = *(const short8*)&Pl[wave][l16 * 40 + quad * 8];
#pragma unroll
            for (int dt = 0; dt < 4; ++dt) {
                short8 vf = *(const short8*)&Vt[(dt * 16 + l16) * 40 + quad * 8];
                O[dt] = __builtin_amdgcn_mfma_f32_16x16x32_bf16(pf, vf, O[dt], 0, 0, 0);
            }
        }
    }
#pragma unroll
    for (int dt = 0; dt < 4; ++dt)
#pragma unroll
        for (int r = 0; r < 4; ++r) {
            int q = q0w + quad * 4 + r;
            float v = O[dt][r] / l_i[r];
            y[((size_t)(b * TS) + q) * EMB + h * 64 + dt * 16 + l16] = f2bf(v);
        }
}

// ---------------- host ---------------------------------------------------------
extern "C" void kernel_launch(void* const* d_in, const int* in_sizes, int n_in,
                              void* d_out, int out_size, void* d_ws, size_t ws_size,
                              hipStream_t stream)
{
    const int*  idx    = (const int*)d_in[0];
    const void* wte    = d_in[1];
    const void* wpe    = d_in[2];
    const void* attn_w = d_in[3];   // [L,512,1536]
    const void* proj_w = d_in[4];   // [L,512,512]
    const void* fc_w   = d_in[5];   // [L,512,2048]
    const void* fcp_w  = d_in[6];   // [L,2048,512]
    const void* ln1_w  = d_in[7];
    const void* ln2_w  = d_in[8];
    const void* lnf_w  = d_in[9];

    const size_t sz_xw   = (size_t)NTOK * EMB * 4;
    const size_t sz_hbf  = (size_t)NTOK * EMB * 2;
    const size_t sz_big  = (size_t)NTOK * 2048 * 2;
    const size_t sz_wteb = (size_t)VOCAB * EMB * 2;          // 379,904 (256-divisible)
    const size_t sz_wbuf = (size_t)3145728 * 2;              // 6.29 MB per-layer bf16 [N,K]
    const size_t need_legacy = 256 + sz_xw + sz_hbf + sz_big;
    const size_t need_fast   = need_legacy + sz_wteb + sz_wbuf;

    if (ws_size < need_legacy) {
        sentinel_k<<<(out_size + 255) / 256, 256, 0, stream>>>((ushort_t*)d_out, out_size);
        return;
    }
    int* flag = (int*)d_ws;
    char* p = (char*)d_ws + 256;
    float*    xw  = (float*)p;    p += sz_xw;
    ushort_t* hbf = (ushort_t*)p; p += sz_hbf;
    ushort_t* big = (ushort_t*)p; p += sz_big;

    detect_k<<<1, 64, 0, stream>>>((const ushort_t*)wte, flag);
    embed_k<<<NTOK, 256, 0, stream>>>(idx, wte, wpe, xw, flag);

    if (ws_size >= need_fast) {
        ushort_t* wteb = (ushort_t*)p; p += sz_wteb;
        ushort_t* wbuf = (ushort_t*)p; p += sz_wbuf;
        wconv_k<<<(VOCAB * EMB + 255) / 256, 256, 0, stream>>>(wte, wteb, VOCAB * EMB, flag);
        for (int l = 0; l < NL; ++l) {
            wtrans_k<<<3072, 256, 0, stream>>>(attn_w, proj_w, fc_w, fcp_w, (long)l, wbuf, flag);
            ln_k<<<NTOK, 256, 0, stream>>>(xw, ln1_w, (long)l * EMB, hbf, flag);
            gemm_nt<<<dim3(24, 64), 256, 0, stream>>>(hbf, wbuf,
                    NTOK, 1536, 512, nullptr, big, nullptr, nullptr, 0, flag);
            attn_k<<<dim3(16, 32), 256, 0, stream>>>(big, hbf);
            gemm_nt<<<dim3(8, 64), 256, 0, stream>>>(hbf, wbuf + 786432,
                    NTOK, 512, 512, xw, nullptr, nullptr, xw, 0, flag);
            ln_k<<<NTOK, 256, 0, stream>>>(xw, ln2_w, (long)l * EMB, hbf, flag);
            gemm_nt<<<dim3(32, 64), 256, 0, stream>>>(hbf, wbuf + 1048576,
                    NTOK, 2048, 512, nullptr, big, nullptr, nullptr, 1 /*gelu*/, flag);
            gemm_nt<<<dim3(8, 64), 256, 0, stream>>>(big, wbuf + 2097152,
                    NTOK, 512, 2048, xw, nullptr, nullptr, xw, 0, flag);
        }
        ln_k<<<NTOK, 256, 0, stream>>>(xw, lnf_w, 0, hbf, flag);
        gemm_nt<<<dim3(6, 64), 256, 0, stream>>>(hbf, wteb,
                NTOK, VOCAB, 512, nullptr, nullptr, d_out, nullptr, 0, flag);
    } else {
        // legacy fallback (proven in r3)
        for (int l = 0; l < NL; ++l) {
            ln_k<<<NTOK, 256, 0, stream>>>(xw, ln1_w, (long)l * EMB, hbf, flag);
            gemm_k<<<dim3(24, 64), 256, 0, stream>>>(hbf, attn_w, (long)l * 512 * 1536,
                    NTOK, 1536, 512, 0, nullptr, big, nullptr, nullptr, 0, flag);
            attn_k<<<dim3(16, 32), 256, 0, stream>>>(big, hbf);
            gemm_k<<<dim3(8, 64), 256, 0, stream>>>(hbf, proj_w, (long)l * 512 * 512,
                    NTOK, 512, 512, 0, xw, nullptr, nullptr, xw, 0, flag);
            ln_k<<<NTOK, 256, 0, stream>>>(xw, ln2_w, (long)l * EMB, hbf, flag);
            gemm_k<<<dim3(32, 64), 256, 0, stream>>>(hbf, fc_w, (long)l * 512 * 2048,
                    NTOK, 2048, 512, 0, nullptr, big, nullptr, nullptr, 1, flag);
            gemm_k<<<dim3(8, 64), 256, 0, stream>>>(big, fcp_w, (long)l * 2048 * 512,
                    NTOK, 512, 2048, 0, xw, nullptr, nullptr, xw, 0, flag);
        }
        ln_k<<<NTOK, 256, 0, stream>>>(xw, lnf_w, 0, hbf, flag);
        gemm_k<<<dim3(6, 64), 256, 0, stream>>>(hbf, wte, 0,
                NTOK, VOCAB, 512, 1, nullptr, nullptr, d_out, nullptr, 0, flag);
    }
}

// Round 5
// 1280.468 us; speedup vs baseline: 1.8873x; 1.1831x over previous
//
#include <hip/hip_runtime.h>

// GPT forward, MI355X gfx950.
// Shapes: V=371 E=512 H=8 L=8 B=4 T=1024 D=64, N=B*T=4096.
// Inputs float32 (runtime-detected, bf16 also supported); output matches input fmt.
// r5: attention rewritten — 64-key tiles, 2 barriers/tile, swizzled V transpose,
// mask-free bulk loop + masked diagonal tile, reversed qt dispatch order.

#define VOCAB 371
#define EMB   512
#define NH    8
#define NL    8
#define TS    1024
#define NTOK  4096
#define NEG_INF (-1e30f)

typedef unsigned short ushort_t;
typedef __attribute__((ext_vector_type(8))) short short8;
typedef __attribute__((ext_vector_type(4))) float f32x4;

__device__ inline float bf2f(ushort_t b) {
    unsigned int u = ((unsigned int)b) << 16;
    float f; __builtin_memcpy(&f, &u, 4); return f;
}
__device__ inline ushort_t f2bf(float f) {
    unsigned int u; __builtin_memcpy(&u, &f, 4);
    u = (u + 0x7fff + ((u >> 16) & 1)) >> 16;   // RNE
    return (ushort_t)u;
}

// ---------------- dtype probe ---------------------------------------------------
__global__ __launch_bounds__(64) void detect_k(const ushort_t* __restrict__ w,
        int* __restrict__ flag)
{
    int i = threadIdx.x;
    float v = bf2f(w[2 * i]);
    bool ok = (__builtin_fabsf(v) <= 4.0f);
    unsigned long long m = __ballot(ok);
    if (i == 0) flag[0] = (__popcll(m) >= 56) ? 1 : 0;   // 1 = bf16, 0 = float32
}

// ---------------- ws-too-small sentinel ----------------------------------------
__global__ __launch_bounds__(256) void sentinel_k(ushort_t* __restrict__ out, int n)
{
    int i = blockIdx.x * 256 + threadIdx.x;
    if (i < n) out[i] = 0x447A;
}

// ---------------- embedding ----------------------------------------------------
__global__ __launch_bounds__(256) void embed_k(const int* __restrict__ idx,
        const void* __restrict__ wte, const void* __restrict__ wpe,
        float* __restrict__ x, const int* __restrict__ flag)
{
    int n = blockIdx.x, tid = threadIdx.x;
    int t = n & (TS - 1);
    int v = idx[n];
    size_t o = (size_t)n * EMB;
    float a0, a1, b0, b1;
    if (*flag) {
        const ushort_t* te = (const ushort_t*)wte; const ushort_t* pe = (const ushort_t*)wpe;
        a0 = bf2f(te[v * EMB + tid]); a1 = bf2f(te[v * EMB + 256 + tid]);
        b0 = bf2f(pe[t * EMB + tid]); b1 = bf2f(pe[t * EMB + 256 + tid]);
    } else {
        const float* te = (const float*)wte; const float* pe = (const float*)wpe;
        a0 = te[v * EMB + tid]; a1 = te[v * EMB + 256 + tid];
        b0 = pe[t * EMB + tid]; b1 = pe[t * EMB + 256 + tid];
    }
    x[o + tid] = a0 + b0;
    x[o + 256 + tid] = a1 + b1;
}

// ---------------- layernorm ----------------------------------------------------
__global__ __launch_bounds__(256) void ln_k(const float* __restrict__ x,
        const void* __restrict__ w, long woff, ushort_t* __restrict__ out,
        const int* __restrict__ flag)
{
    __shared__ float red[8];
    int n = blockIdx.x, tid = threadIdx.x;
    const float* xr = x + (size_t)n * EMB;
    float a = xr[tid], b = xr[tid + 256];
    float s = a + b;
#pragma unroll
    for (int off = 32; off > 0; off >>= 1) s += __shfl_down(s, off, 64);
    if ((tid & 63) == 0) red[tid >> 6] = s;
    __syncthreads();
    float mean = (red[0] + red[1] + red[2] + red[3]) * (1.0f / EMB);
    float da = a - mean, db = b - mean;
    float s2 = da * da + db * db;
#pragma unroll
    for (int off = 32; off > 0; off >>= 1) s2 += __shfl_down(s2, off, 64);
    if ((tid & 63) == 0) red[4 + (tid >> 6)] = s2;
    __syncthreads();
    float var = (red[4] + red[5] + red[6] + red[7]) * (1.0f / EMB);
    float rs = rsqrtf(var + 1e-5f);
    float g0, g1;
    if (*flag) {
        const ushort_t* wb = (const ushort_t*)w + woff;
        g0 = bf2f(wb[tid]); g1 = bf2f(wb[tid + 256]);
    } else {
        const float* wf = (const float*)w + woff;
        g0 = wf[tid]; g1 = wf[tid + 256];
    }
    size_t o = (size_t)n * EMB;
    out[o + tid]       = f2bf(da * rs * g0);
    out[o + 256 + tid] = f2bf(db * rs * g1);
}

// ---------------- weight transpose+convert: [K,N] dtype -> bf16 [N,K] ----------
// l >= 0: single layer l, output at wbuf (per-layer mode, grid z=1).
// l <  0: all layers, layer = blockIdx.z, output at wbuf + z*3145728.
__global__ __launch_bounds__(256) void wtrans_k(const void* __restrict__ aw,
        const void* __restrict__ pw, const void* __restrict__ fw,
        const void* __restrict__ fpw, long l, ushort_t* __restrict__ wbuf,
        const int* __restrict__ flag)
{
    __shared__ float tile[32][33];
    const int isbf = *flag;
    long lay = (l < 0) ? (long)blockIdx.z : l;
    ushort_t* obase = wbuf + ((l < 0) ? (size_t)blockIdx.z * 3145728 : 0);
    int t = blockIdx.x;
    const void* src; ushort_t* dst; int Kw, Nw; long ioff;
    if (t < 768)       { src = aw;  dst = obase;           Kw = 512;  Nw = 1536; ioff = lay * 512L * 1536; }
    else if (t < 1024) { t -= 768;  src = pw;  dst = obase + 786432;  Kw = 512;  Nw = 512;  ioff = lay * 512L * 512; }
    else if (t < 2048) { t -= 1024; src = fw;  dst = obase + 1048576; Kw = 512;  Nw = 2048; ioff = lay * 512L * 2048; }
    else               { t -= 2048; src = fpw; dst = obase + 2097152; Kw = 2048; Nw = 512;  ioff = lay * 2048L * 512; }
    int tpn = Nw >> 5;
    int n0 = (t % tpn) * 32, k0 = (t / tpn) * 32;
    int tx = threadIdx.x & 31, ty = threadIdx.x >> 5;
#pragma unroll
    for (int i = 0; i < 4; ++i) {
        int r = ty + i * 8;
        size_t ii = ioff + (size_t)(k0 + r) * Nw + n0 + tx;
        tile[r][tx] = isbf ? bf2f(((const ushort_t*)src)[ii]) : ((const float*)src)[ii];
    }
    __syncthreads();
#pragma unroll
    for (int i = 0; i < 4; ++i)
        dst[(size_t)(n0 + ty + i * 8) * Kw + k0 + tx] = f2bf(tile[tx][ty + i * 8]);
}

// ---------------- wte convert --------------------------------------------------
__global__ __launch_bounds__(256) void wconv_k(const void* __restrict__ in,
        ushort_t* __restrict__ out, int n, const int* __restrict__ flag)
{
    int i = blockIdx.x * 256 + threadIdx.x;
    if (i >= n) return;
    out[i] = (*flag) ? ((const ushort_t*)in)[i] : f2bf(((const float*)in)[i]);
}

// ---------------- fast NT GEMM: C[M,N] = A[M,K](bf16) * Bt[N,K](bf16)^T --------
__global__ __launch_bounds__(256) void gemm_nt(const ushort_t* __restrict__ A,
        const ushort_t* __restrict__ Bt, int M, int N, int K,
        float* __restrict__ outF, ushort_t* __restrict__ outB, void* __restrict__ outD,
        const float* __restrict__ res, int act, const int* __restrict__ flag)
{
    __shared__ ushort_t Al[64 * 72];
    __shared__ ushort_t Bl[64 * 72];
    const int isbf = *flag;
    const int tid = threadIdx.x;
    const int wave = tid >> 6, lane = tid & 63;
    const int quad = lane >> 4, l16 = lane & 15;
    const int m0 = blockIdx.y * 64, n0 = blockIdx.x * 64;
    const int sr = tid >> 2, sc = (tid & 3) * 16;
    const bool bok = (n0 + sr) < N;
    const ushort_t* Ag = A + (size_t)(m0 + sr) * K + sc;
    const ushort_t* Bg = Bt + (size_t)(n0 + sr) * K + sc;
    f32x4 acc[4] = {};
    for (int k0 = 0; k0 < K; k0 += 64) {
        uint4 a0 = *(const uint4*)(Ag + k0);
        uint4 a1 = *(const uint4*)(Ag + k0 + 8);
        uint4 b0 = make_uint4(0, 0, 0, 0), b1 = make_uint4(0, 0, 0, 0);
        if (bok) { b0 = *(const uint4*)(Bg + k0); b1 = *(const uint4*)(Bg + k0 + 8); }
        __syncthreads();
        *(uint4*)&Al[sr * 72 + sc] = a0; *(uint4*)&Al[sr * 72 + sc + 8] = a1;
        *(uint4*)&Bl[sr * 72 + sc] = b0; *(uint4*)&Bl[sr * 72 + sc + 8] = b1;
        __syncthreads();
#pragma unroll
        for (int kc = 0; kc < 2; ++kc) {
            short8 af = *(const short8*)&Al[(wave * 16 + l16) * 72 + kc * 32 + quad * 8];
#pragma unroll
            for (int nt = 0; nt < 4; ++nt) {
                short8 bf = *(const short8*)&Bl[(nt * 16 + l16) * 72 + kc * 32 + quad * 8];
                acc[nt] = __builtin_amdgcn_mfma_f32_16x16x32_bf16(af, bf, acc[nt], 0, 0, 0);
            }
        }
    }
    const int mb = m0 + wave * 16 + quad * 4;
#pragma unroll
    for (int nt = 0; nt < 4; ++nt) {
        int nn = n0 + nt * 16 + l16;
        if (nn >= N) continue;
#pragma unroll
        for (int r = 0; r < 4; ++r) {
            size_t o = (size_t)(mb + r) * N + nn;
            float v = acc[nt][r];
            if (res) v += res[o];
            if (act) v = 0.5f * v * (1.0f + erff(v * 0.70710678118f));
            if (outF)      outF[o] = v;
            else if (outB) outB[o] = f2bf(v);
            else if (isbf) ((ushort_t*)outD)[o] = f2bf(v);
            else           ((float*)outD)[o] = v;
        }
    }
}

// ---------------- legacy GEMM (fallback) ---------------------------------------
__global__ __launch_bounds__(256) void gemm_k(const ushort_t* __restrict__ A,
        const void* __restrict__ B, long boff, int M, int N, int K, int bt,
        float* __restrict__ outF, ushort_t* __restrict__ outB, void* __restrict__ outD,
        const float* __restrict__ res, int act, const int* __restrict__ flag)
{
    __shared__ ushort_t Al[64 * 40];
    __shared__ ushort_t Bl[64 * 40];
    const int isbf = *flag;
    const int tid = threadIdx.x;
    const int wave = tid >> 6, lane = tid & 63;
    const int quad = lane >> 4, l16 = lane & 15;
    const int m0 = blockIdx.y * 64, n0 = blockIdx.x * 64;
    const int sr = tid >> 2, sc = (tid & 3) * 8;
    const int kr = tid >> 3, nc = (tid & 7) * 8;
    f32x4 acc[4] = {};
    const bool bok = (n0 + sr) < N;
    const ushort_t* Ag = A + (size_t)(m0 + sr) * K + sc;
    const ushort_t* Bb = (const ushort_t*)B + boff;
    const float*    Bf = (const float*)B + boff;
    const size_t i1 = (size_t)(n0 + sr) * K + sc;
    const size_t i0 = (size_t)kr * N + n0 + nc;
    for (int k0 = 0; k0 < K; k0 += 32) {
        uint4 av = *(const uint4*)(Ag + k0);
        ushort_t b8[8] = {0, 0, 0, 0, 0, 0, 0, 0};
        size_t bi = bt ? (i1 + k0) : (i0 + (size_t)k0 * N);
        if (!bt || bok) {
            if (isbf) *(uint4*)b8 = *(const uint4*)(Bb + bi);
            else {
                float4 f0 = *(const float4*)(Bf + bi);
                float4 f1 = *(const float4*)(Bf + bi + 4);
                b8[0] = f2bf(f0.x); b8[1] = f2bf(f0.y); b8[2] = f2bf(f0.z); b8[3] = f2bf(f0.w);
                b8[4] = f2bf(f1.x); b8[5] = f2bf(f1.y); b8[6] = f2bf(f1.z); b8[7] = f2bf(f1.w);
            }
        }
        __syncthreads();
        *(uint4*)&Al[sr * 40 + sc] = av;
        if (bt) *(uint4*)&Bl[sr * 40 + sc] = *(uint4*)b8;
        else {
#pragma unroll
            for (int i = 0; i < 8; ++i) Bl[(nc + i) * 40 + kr] = b8[i];
        }
        __syncthreads();
        short8 af = *(const short8*)&Al[(wave * 16 + l16) * 40 + quad * 8];
#pragma unroll
        for (int nt = 0; nt < 4; ++nt) {
            short8 bf = *(const short8*)&Bl[(nt * 16 + l16) * 40 + quad * 8];
            acc[nt] = __builtin_amdgcn_mfma_f32_16x16x32_bf16(af, bf, acc[nt], 0, 0, 0);
        }
    }
    const int mb = m0 + wave * 16 + quad * 4;
#pragma unroll
    for (int nt = 0; nt < 4; ++nt) {
        int nn = n0 + nt * 16 + l16;
        if (nn >= N) continue;
#pragma unroll
        for (int r = 0; r < 4; ++r) {
            size_t o = (size_t)(mb + r) * N + nn;
            float v = acc[nt][r];
            if (res) v += res[o];
            if (act) v = 0.5f * v * (1.0f + erff(v * 0.70710678118f));
            if (outF)      outF[o] = v;
            else if (outB) outB[o] = f2bf(v);
            else if (isbf) ((ushort_t*)outD)[o] = f2bf(v);
            else           ((float*)outD)[o] = v;
        }
    }
}

// ---------------- flash attention v2 (causal), 64-key tiles --------------------
// qkv bf16 [N,1536] rows = [q|k|v]; grid (16, B*H); 256 thr, wave w owns 16 q-rows.
// Bulk tiles (kt<qt) mask-free; diagonal tile masked. 2 barriers/tile.
// Vt stored with per-(d>>3) column swizzle so pair-packed b32 staging writes are
// 2 lanes/bank (free). Pl is per-wave: P write -> PV read is wave-synchronous.
__global__ __launch_bounds__(256) void attn_k(const ushort_t* __restrict__ qkv,
        ushort_t* __restrict__ y)
{
    __shared__ ushort_t Kl[64 * 72];      // [key][d]
    __shared__ ushort_t Vt[64 * 72];      // [d][swizzled key]
    __shared__ ushort_t Pl[4][16 * 72];   // per-wave [q][key]
    const int tid = threadIdx.x, wave = tid >> 6, lane = tid & 63;
    const int quad = lane >> 4, l16 = lane & 15;
    const int qt = (int)gridDim.x - 1 - blockIdx.x;    // long blocks dispatch first
    const int b = blockIdx.y >> 3, h = blockIdx.y & 7;
    const int q0b = qt * 64;
    const int q0w = q0b + wave * 16;
    const size_t rstr = 3 * EMB;
    const ushort_t* qbase = qkv + ((size_t)(b * TS) + q0w + l16) * rstr + h * 64;
    short8 qf0 = *(const short8*)(qbase + quad * 8);
    short8 qf1 = *(const short8*)(qbase + 32 + quad * 8);
    f32x4 O[4] = {};
    float m_i[4], l_i[4];
#pragma unroll
    for (int r = 0; r < 4; ++r) { m_i[r] = NEG_INF; l_i[r] = 0.f; }
    // staging: K by (key, 16d); V by (key-pair, 8d) with swizzled pair writes
    const int sk = tid >> 2, sdc = (tid & 3) * 16;
    const int vp = tid >> 3, vdc = (tid & 7) * 8;
    const int vsh = 16 * ((tid & 7) & 3);              // = 16*((d>>3)&3), d=vdc+i
    const int vcol = (2 * vp + vsh) & 63;
    for (int kt = 0; kt <= qt; ++kt) {
        const int k0 = kt * 64;
        const ushort_t* krow = qkv + ((size_t)(b * TS) + k0 + sk) * rstr + EMB + h * 64 + sdc;
        uint4 kv0 = *(const uint4*)krow;
        uint4 kv1 = *(const uint4*)(krow + 8);
        const ushort_t* vrow = qkv + ((size_t)(b * TS) + k0 + 2 * vp) * rstr + 2 * EMB + h * 64 + vdc;
        uint4 vv0 = *(const uint4*)vrow;
        uint4 vv1 = *(const uint4*)(vrow + rstr);
        __syncthreads();                               // prior tile's LDS reads done
        *(uint4*)&Kl[sk * 72 + sdc]     = kv0;
        *(uint4*)&Kl[sk * 72 + sdc + 8] = kv1;
        {
            ushort_t v0[8], v1[8];
            *(uint4*)v0 = vv0; *(uint4*)v1 = vv1;
#pragma unroll
            for (int i = 0; i < 8; ++i) {
                unsigned pk = (unsigned)v0[i] | ((unsigned)v1[i] << 16);
                *(unsigned*)&Vt[(vdc + i) * 72 + vcol] = pk;
            }
        }
        __syncthreads();                               // staging visible
        float p[4][4];
        if (kt < qt) {                                 // ---- bulk tile: no masking
            f32x4 S[4] = {};
#pragma unroll
            for (int nt = 0; nt < 4; ++nt) {
                short8 kf0 = *(const short8*)&Kl[(nt * 16 + l16) * 72 + quad * 8];
                short8 kf1 = *(const short8*)&Kl[(nt * 16 + l16) * 72 + 32 + quad * 8];
                S[nt] = __builtin_amdgcn_mfma_f32_16x16x32_bf16(qf0, kf0, S[nt], 0, 0, 0);
                S[nt] = __builtin_amdgcn_mfma_f32_16x16x32_bf16(qf1, kf1, S[nt], 0, 0, 0);
            }
#pragma unroll
            for (int r = 0; r < 4; ++r) {
                float s0 = S[0][r] * 0.125f, s1 = S[1][r] * 0.125f;
                float s2 = S[2][r] * 0.125f, s3 = S[3][r] * 0.125f;
                float mx = fmaxf(fmaxf(s0, s1), fmaxf(s2, s3));
#pragma unroll
                for (int off = 8; off; off >>= 1) mx = fmaxf(mx, __shfl_xor(mx, off, 64));
                float mnew = fmaxf(m_i[r], mx);
                float alpha = __expf(m_i[r] - mnew);
                p[0][r] = __expf(s0 - mnew); p[1][r] = __expf(s1 - mnew);
                p[2][r] = __expf(s2 - mnew); p[3][r] = __expf(s3 - mnew);
                float rsum = (p[0][r] + p[1][r]) + (p[2][r] + p[3][r]);
#pragma unroll
                for (int off = 8; off; off >>= 1) rsum += __shfl_xor(rsum, off, 64);
                l_i[r] = l_i[r] * alpha + rsum;
                m_i[r] = mnew;
#pragma unroll
                for (int dt = 0; dt < 4; ++dt) O[dt][r] *= alpha;
            }
        } else {                                       // ---- diagonal tile: masked
            f32x4 S[4] = {};
#pragma unroll
            for (int nt = 0; nt < 4; ++nt) {
                if (nt > wave) continue;               // fully masked sub-tiles
                short8 kf0 = *(const short8*)&Kl[(nt * 16 + l16) * 72 + quad * 8];
                short8 kf1 = *(const short8*)&Kl[(nt * 16 + l16) * 72 + 32 + quad * 8];
                S[nt] = __builtin_amdgcn_mfma_f32_16x16x32_bf16(qf0, kf0, S[nt], 0, 0, 0);
                S[nt] = __builtin_amdgcn_mfma_f32_16x16x32_bf16(qf1, kf1, S[nt], 0, 0, 0);
            }
#pragma unroll
            for (int r = 0; r < 4; ++r) {
                float s[4];
#pragma unroll
                for (int nt = 0; nt < 4; ++nt) {
                    s[nt] = (nt < wave) ? S[nt][r] * 0.125f
                          : (nt == wave && l16 <= quad * 4 + r) ? S[nt][r] * 0.125f
                          : NEG_INF;
                }
                float mx = fmaxf(fmaxf(s[0], s[1]), fmaxf(s[2], s[3]));
#pragma unroll
                for (int off = 8; off; off >>= 1) mx = fmaxf(mx, __shfl_xor(mx, off, 64));
                float mnew = fmaxf(m_i[r], mx);
                float alpha = __expf(m_i[r] - mnew);
#pragma unroll
                for (int nt = 0; nt < 4; ++nt) p[nt][r] = __expf(s[nt] - mnew);
                float rsum = (p[0][r] + p[1][r]) + (p[2][r] + p[3][r]);
#pragma unroll
                for (int off = 8; off; off >>= 1) rsum += __shfl_xor(rsum, off, 64);
                l_i[r] = l_i[r] * alpha + rsum;
                m_i[r] = mnew;
#pragma unroll
                for (int dt = 0; dt < 4; ++dt) O[dt][r] *= alpha;
            }
        }
        // P -> LDS (C-layout: row=quad*4+r, col=nt*16+l16); per-wave buffer, no barrier
#pragma unroll
        for (int nt = 0; nt < 4; ++nt)
#pragma unroll
            for (int r = 0; r < 4; ++r)
                Pl[wave][(quad * 4 + r) * 72 + nt * 16 + l16] = f2bf(p[nt][r]);
        // PV: 2 key-chunks of 32, 4 d-tiles; Vt read un-swizzles with sh(d)
#pragma unroll
        for (int kc = 0; kc < 2; ++kc) {
            short8 pf = *(const short8*)&Pl[wave][l16 * 72 + kc * 32 + quad * 8];
#pragma unroll
            for (int dt = 0; dt < 4; ++dt) {
                int d = dt * 16 + l16;
                int sh = ((2 * dt + (l16 >> 3)) & 3) * 16;
                int col = (kc * 32 + quad * 8 + sh) & 63;
                short8 vf = *(const short8*)&Vt[d * 72 + col];
                O[dt] = __builtin_amdgcn_mfma_f32_16x16x32_bf16(pf, vf, O[dt], 0, 0, 0);
            }
        }
    }
#pragma unroll
    for (int dt = 0; dt < 4; ++dt)
#pragma unroll
        for (int r = 0; r < 4; ++r) {
            int q = q0w + quad * 4 + r;
            float v = O[dt][r] / l_i[r];
            y[((size_t)(b * TS) + q) * EMB + h * 64 + dt * 16 + l16] = f2bf(v);
        }
}

// ---------------- host ---------------------------------------------------------
extern "C" void kernel_launch(void* const* d_in, const int* in_sizes, int n_in,
                              void* d_out, int out_size, void* d_ws, size_t ws_size,
                              hipStream_t stream)
{
    const int*  idx    = (const int*)d_in[0];
    const void* wte    = d_in[1];
    const void* wpe    = d_in[2];
    const void* attn_w = d_in[3];   // [L,512,1536]
    const void* proj_w = d_in[4];   // [L,512,512]
    const void* fc_w   = d_in[5];   // [L,512,2048]
    const void* fcp_w  = d_in[6];   // [L,2048,512]
    const void* ln1_w  = d_in[7];
    const void* ln2_w  = d_in[8];
    const void* lnf_w  = d_in[9];

    const size_t sz_xw    = (size_t)NTOK * EMB * 4;
    const size_t sz_hbf   = (size_t)NTOK * EMB * 2;
    const size_t sz_big   = (size_t)NTOK * 2048 * 2;
    const size_t sz_wteb  = (size_t)VOCAB * EMB * 2;
    const size_t sz_wbuf1 = (size_t)3145728 * 2;         // per-layer bf16 [N,K]
    const size_t need_legacy = 256 + sz_xw + sz_hbf + sz_big;
    const size_t need_fast   = need_legacy + sz_wteb + sz_wbuf1;
    const size_t need_all    = need_legacy + sz_wteb + NL * sz_wbuf1;   // ~80 MB

    if (ws_size < need_legacy) {
        sentinel_k<<<(out_size + 255) / 256, 256, 0, stream>>>((ushort_t*)d_out, out_size);
        return;
    }
    int* flag = (int*)d_ws;
    char* p = (char*)d_ws + 256;
    float*    xw  = (float*)p;    p += sz_xw;
    ushort_t* hbf = (ushort_t*)p; p += sz_hbf;
    ushort_t* big = (ushort_t*)p; p += sz_big;

    detect_k<<<1, 64, 0, stream>>>((const ushort_t*)wte, flag);
    embed_k<<<NTOK, 256, 0, stream>>>(idx, wte, wpe, xw, flag);

    if (ws_size >= need_fast) {
        ushort_t* wteb = (ushort_t*)p; p += sz_wteb;
        ushort_t* wbuf = (ushort_t*)p;
        const bool allw = (ws_size >= need_all);
        wconv_k<<<(VOCAB * EMB + 255) / 256, 256, 0, stream>>>(wte, wteb, VOCAB * EMB, flag);
        if (allw)
            wtrans_k<<<dim3(3072, 1, NL), 256, 0, stream>>>(attn_w, proj_w, fc_w, fcp_w,
                    -1, wbuf, flag);
        for (int l = 0; l < NL; ++l) {
            ushort_t* wb = allw ? (wbuf + (size_t)l * 3145728) : wbuf;
            if (!allw)
                wtrans_k<<<dim3(3072, 1, 1), 256, 0, stream>>>(attn_w, proj_w, fc_w, fcp_w,
                        (long)l, wbuf, flag);
            ln_k<<<NTOK, 256, 0, stream>>>(xw, ln1_w, (long)l * EMB, hbf, flag);
            gemm_nt<<<dim3(24, 64), 256, 0, stream>>>(hbf, wb,
                    NTOK, 1536, 512, nullptr, big, nullptr, nullptr, 0, flag);
            attn_k<<<dim3(16, 32), 256, 0, stream>>>(big, hbf);
            gemm_nt<<<dim3(8, 64), 256, 0, stream>>>(hbf, wb + 786432,
                    NTOK, 512, 512, xw, nullptr, nullptr, xw, 0, flag);
            ln_k<<<NTOK, 256, 0, stream>>>(xw, ln2_w, (long)l * EMB, hbf, flag);
            gemm_nt<<<dim3(32, 64), 256, 0, stream>>>(hbf, wb + 1048576,
                    NTOK, 2048, 512, nullptr, big, nullptr, nullptr, 1 /*gelu*/, flag);
            gemm_nt<<<dim3(8, 64), 256, 0, stream>>>(big, wb + 2097152,
                    NTOK, 512, 2048, xw, nullptr, nullptr, xw, 0, flag);
        }
        ln_k<<<NTOK, 256, 0, stream>>>(xw, lnf_w, 0, hbf, flag);
        gemm_nt<<<dim3(6, 64), 256, 0, stream>>>(hbf, wteb,
                NTOK, VOCAB, 512, nullptr, nullptr, d_out, nullptr, 0, flag);
    } else {
        for (int l = 0; l < NL; ++l) {
            ln_k<<<NTOK, 256, 0, stream>>>(xw, ln1_w, (long)l * EMB, hbf, flag);
            gemm_k<<<dim3(24, 64), 256, 0, stream>>>(hbf, attn_w, (long)l * 512 * 1536,
                    NTOK, 1536, 512, 0, nullptr, big, nullptr, nullptr, 0, flag);
            attn_k<<<dim3(16, 32), 256, 0, stream>>>(big, hbf);
            gemm_k<<<dim3(8, 64), 256, 0, stream>>>(hbf, proj_w, (long)l * 512 * 512,
                    NTOK, 512, 512, 0, xw, nullptr, nullptr, xw, 0, flag);
            ln_k<<<NTOK, 256, 0, stream>>>(xw, ln2_w, (long)l * EMB, hbf, flag);
            gemm_k<<<dim3(32, 64), 256, 0, stream>>>(hbf, fc_w, (long)l * 512 * 2048,
                    NTOK, 2048, 512, 0, nullptr, big, nullptr, nullptr, 1, flag);
            gemm_k<<<dim3(8, 64), 256, 0, stream>>>(big, fcp_w, (long)l * 2048 * 512,
                    NTOK, 512, 2048, 0, xw, nullptr, nullptr, xw, 0, flag);
        }
        ln_k<<<NTOK, 256, 0, stream>>>(xw, lnf_w, 0, hbf, flag);
        gemm_k<<<dim3(6, 64), 256, 0, stream>>>(hbf, wte, 0,
                NTOK, VOCAB, 512, 1, nullptr, nullptr, d_out, nullptr, 0, flag);
    }
}